// Round 4
// baseline (171.271 us; speedup 1.0000x reference)
//
#include <hip/hip_runtime.h>
#include <math.h>

// Problem constants
#define NB   16
#define NC   64
#define HWs  4096
#define NPS  1024
#define LOG2E 1.44269504088896341f

// ws layout in ushort (bf16 bit patterns)
static constexpr size_t PHI_OFF = (size_t)NB * HWs * 8;            // theta: [b][4096][8]
static constexpr size_t GT_OFF  = PHI_OFF + (size_t)NB * NPS * 8;  // phi:   [b][1024][8]
// gT: [b][32][1024]; total 1,179,648 ushorts = 2.25 MB

typedef short s16x8 __attribute__((ext_vector_type(8)));
typedef float f32x4 __attribute__((ext_vector_type(4)));

#define LD8G(p) (*(const s16x8*)(p))

__device__ inline unsigned short f2bf(float f) {
    unsigned int u = __float_as_uint(f);
    u += 0x7fffu + ((u >> 16) & 1u);          // RNE
    return (unsigned short)(u >> 16);
}
__device__ inline unsigned int pk2(float a, float b) {
    unsigned int ua = __float_as_uint(a); ua += 0x7fffu + ((ua >> 16) & 1u);
    unsigned int ub = __float_as_uint(b); ub += 0x7fffu + ((ub >> 16) & 1u);
    return (ua >> 16) | (ub & 0xffff0000u);
}

// ---------------------------------------------------------------------------
// Kernel 1 (v2): all projections in one pass, x staged through LDS.
// Block = (b, row-pair): 16 x 32 = 512 blocks. x-tile [64 ch][128 px] fp32
// staged with 8 coalesced float4 loads per thread (read x ONCE).
// Thread: h = tid&127 -> (row = h&1, col = h>>1), half = tid>>7.
//   half0: theta (8 ch, *log2e) at its px + g channels 0..15
//   half1: phi (8 ch) + g channels 16..31
// Pooling: conv first, then max via shfl_xor(1) [row pair] + shfl_xor(2)
// [col pair]; lanes h%4==0 hold pooled ps = rp*32 + (h>>2).
// ---------------------------------------------------------------------------
__global__ __launch_bounds__(256) void k_proj(
    const float* __restrict__ x, const float* __restrict__ Wt,
    const float* __restrict__ Wp, const float* __restrict__ Wg,
    unsigned short* __restrict__ ws)
{
    __shared__ float xs[64 * 128];            // 32 KB

    unsigned short* theta = ws;
    unsigned short* phi   = ws + PHI_OFF;
    unsigned short* gT    = ws + GT_OFF;

    const int tid = threadIdx.x;
    const int blk = blockIdx.x;
    const int b   = blk >> 5;
    const int rp  = blk & 31;                 // image rows {2rp, 2rp+1}

    // ---- stage x[b][ci][rp*128 .. +128) -> xs[ci][0..128) ----
    const float* xsrc = x + (size_t)b * NC * HWs + rp * 128;
#pragma unroll
    for (int i = 0; i < 8; ++i) {
        const int idx = i * 256 + tid;        // 0..2047 float4 slots
        const int ci  = idx >> 5;
        const int f4  = idx & 31;
        float4 v = *(const float4*)(xsrc + (size_t)ci * HWs + f4 * 4);
        *(float4*)(xs + ci * 128 + f4 * 4) = v;
    }
    __syncthreads();

    const int h    = tid & 127;
    const int half = tid >> 7;                // wave-uniform
    const int row  = h & 1;
    const int col  = h >> 1;
    const int px   = row * 64 + col;

    float a8[8], ag[16];
#pragma unroll
    for (int j = 0; j < 8; ++j)  a8[j] = 0.f;
#pragma unroll
    for (int j = 0; j < 16; ++j) ag[j] = 0.f;

    const float* W8 = half ? Wp : Wt;
    const float* WG = Wg + half * 16 * NC;    // rows 0..15 / 16..31

#pragma unroll 4
    for (int ci = 0; ci < NC; ++ci) {
        const float xv = xs[ci * 128 + px];   // 2-way bank alias: free
#pragma unroll
        for (int j = 0; j < 8; ++j)  a8[j] += W8[j * NC + ci] * xv;   // scalar
#pragma unroll
        for (int j = 0; j < 16; ++j) ag[j] += WG[j * NC + ci] * xv;   // scalar
    }

    if (half == 0) {
        // theta: unpooled, scaled by log2e
        const int q = (2 * rp + row) * 64 + col;
        uint4 pkd;
        pkd.x = pk2(a8[0] * LOG2E, a8[1] * LOG2E);
        pkd.y = pk2(a8[2] * LOG2E, a8[3] * LOG2E);
        pkd.z = pk2(a8[4] * LOG2E, a8[5] * LOG2E);
        pkd.w = pk2(a8[6] * LOG2E, a8[7] * LOG2E);
        *(uint4*)(theta + ((size_t)b * HWs + q) * 8) = pkd;
    }

    // pooled max: row pair (h^1) then col pair (h^2) — both within-wave
#pragma unroll
    for (int j = 0; j < 8; ++j) {
        float v = a8[j];
        v = fmaxf(v, __shfl_xor(v, 1));
        v = fmaxf(v, __shfl_xor(v, 2));
        a8[j] = v;
    }
#pragma unroll
    for (int j = 0; j < 16; ++j) {
        float v = ag[j];
        v = fmaxf(v, __shfl_xor(v, 1));
        v = fmaxf(v, __shfl_xor(v, 2));
        ag[j] = v;
    }

    if ((h & 3) == 0) {
        const int ps = rp * 32 + (h >> 2);
        if (half == 1) {
            uint4 pkd;
            pkd.x = pk2(a8[0], a8[1]); pkd.y = pk2(a8[2], a8[3]);
            pkd.z = pk2(a8[4], a8[5]); pkd.w = pk2(a8[6], a8[7]);
            *(uint4*)(phi + ((size_t)b * NPS + ps) * 8) = pkd;
        }
#pragma unroll
        for (int j = 0; j < 16; ++j) {
            const int c = half * 16 + j;
            gT[((size_t)b * 32 + c) * NPS + ps] = f2bf(ag[j]);
        }
    }
}

// ---------------------------------------------------------------------------
// Kernel 2 (v2): MFMA attention, NO online softmax (scores are small by
// construction: |S*log2e| < ~6, so exp2 with no max-subtraction is safe).
// Block = (b, 64-q tile): 1024 blocks; wave owns 16 q. Per 64-key tile:
//   S = mfma(A=theta, B=phi) x4     -> D[q=quad*4+r][s=ss*16+lr]  (round-3-verified)
//   p = exp2(S); l4[r] += p  (l in EXACTLY the O register layout — no bridge)
//   P -> bf16 trunc -> wave-private LDS [16 q][72 s]
//   O += mfma(A=P from LDS, B=gT from global) x4
// End: 4-shfl butterfly on l4, O *= 1/l in-register. Wo epilogue + residual.
// ---------------------------------------------------------------------------
__global__ __launch_bounds__(256) void k_attn(
    const float* __restrict__ x, const float* __restrict__ Wo,
    const float* __restrict__ gamma_p, const unsigned short* __restrict__ ws,
    float* __restrict__ out)
{
    __shared__ __align__(16) unsigned char smem[9216];  // P: 4 waves x 16 x 72 x 2B; epilogue otile[32][68] f32

    const int tid  = threadIdx.x;
    const int wave = tid >> 6, lane = tid & 63;
    const int quad = lane >> 4, lr = lane & 15;
    const int blk  = blockIdx.x;
    const int b    = blk >> 6;
    const int q0   = (blk & 63) * 64;

    const unsigned short* th = ws + (size_t)b * HWs * 8;
    const unsigned short* ph = ws + PHI_OFF + (size_t)b * NPS * 8;
    const unsigned short* gp = ws + GT_OFF + (size_t)b * 32 * NPS;
    unsigned short* Pw = (unsigned short*)smem + wave * 1152;   // [16 q][72 s]

    const s16x8 zf = {0, 0, 0, 0, 0, 0, 0, 0};

    // theta A-fragment: A[m=q=lr][k=quad*8+j], real k<8 in quad 0
    const s16x8 thA = (quad == 0) ? LD8G(th + (size_t)(q0 + wave * 16 + lr) * 8) : zf;

    f32x4 O[2];
    f32x4 l4;
#pragma unroll
    for (int r = 0; r < 4; ++r) { O[0][r] = 0.f; O[1][r] = 0.f; l4[r] = 0.f; }

    for (int t = 0; t < 16; ++t) {
        const int s0 = t * 64;

        // phi B-fragments: B[n=s=lr][k=quad*8+j], real k<8 in quad 0
        s16x8 phB[4];
#pragma unroll
        for (int ss = 0; ss < 4; ++ss)
            phB[ss] = (quad == 0) ? LD8G(ph + (size_t)(s0 + ss * 16 + lr) * 8) : zf;

        // scores: D[q][s]; lane reg r holds S[q = quad*4+r][s = ss*16+lr]
        const f32x4 zc = {0.f, 0.f, 0.f, 0.f};
        f32x4 S[4];
#pragma unroll
        for (int ss = 0; ss < 4; ++ss)
            S[ss] = __builtin_amdgcn_mfma_f32_16x16x32_bf16(thA, phB[ss], zc, 0, 0, 0);

        // p = exp2(S) (theta pre-scaled by log2e), accumulate l, store bf16 P
#pragma unroll
        for (int ss = 0; ss < 4; ++ss)
#pragma unroll
            for (int r = 0; r < 4; ++r) {
                const float p = exp2f(S[ss][r]);
                l4[r] += p;
                Pw[(quad * 4 + r) * 72 + ss * 16 + lr] =
                    (unsigned short)(__float_as_uint(p) >> 16);   // truncate
            }

        // PV: A = P[q=lr][k=s] from LDS; B = G[n=c=cs*16+lr][k=s] from gT
#pragma unroll
        for (int kc = 0; kc < 2; ++kc) {
            s16x8 Gf[2];
#pragma unroll
            for (int cs = 0; cs < 2; ++cs)
                Gf[cs] = LD8G(gp + (size_t)(cs * 16 + lr) * NPS + s0 + kc * 32 + quad * 8);
            const s16x8 Pf = *(const s16x8*)(Pw + lr * 72 + kc * 32 + quad * 8);
#pragma unroll
            for (int cs = 0; cs < 2; ++cs)
                O[cs] = __builtin_amdgcn_mfma_f32_16x16x32_bf16(Pf, Gf[cs], O[cs], 0, 0, 0);
        }
    }

    // l: butterfly-sum over the 16-lane s-groups; O rows share the same q map
#pragma unroll
    for (int r = 0; r < 4; ++r) {
        float v = l4[r];
        v += __shfl_xor(v, 1);
        v += __shfl_xor(v, 2);
        v += __shfl_xor(v, 4);
        v += __shfl_xor(v, 8);
        l4[r] = 1.f / v;
    }

    __syncthreads();                          // all waves done reading their Pw
    float* otile = (float*)smem;              // [32 c][68 q-stride]
#pragma unroll
    for (int cs = 0; cs < 2; ++cs) {
        f32x4 v;
#pragma unroll
        for (int r = 0; r < 4; ++r) v[r] = O[cs][r] * l4[r];
        *(f32x4*)(otile + (cs * 16 + lr) * 68 + wave * 16 + quad * 4) = v;
    }
    __syncthreads();

    // Wo epilogue + residual: thread = (q = tid&63, oc quarter = tid>>6)
    const int qq = tid & 63;
    const int quarter = tid >> 6;
    float acc[16];
#pragma unroll
    for (int j = 0; j < 16; ++j) acc[j] = 0.f;
    for (int c = 0; c < 32; ++c) {
        const float ov = otile[c * 68 + qq];
#pragma unroll
        for (int j = 0; j < 16; ++j)
            acc[j] += Wo[(quarter * 16 + j) * 32 + c] * ov;   // wave-uniform -> s_load
    }
    const float gam = gamma_p[0];
#pragma unroll
    for (int j = 0; j < 16; ++j) {
        const size_t a = ((size_t)b * NC + quarter * 16 + j) * HWs + q0 + qq;
        out[a] = gam * acc[j] + x[a];
    }
}

extern "C" void kernel_launch(void* const* d_in, const int* in_sizes, int n_in,
                              void* d_out, int out_size, void* d_ws, size_t ws_size,
                              hipStream_t stream) {
    const float* x     = (const float*)d_in[0];
    const float* Wt    = (const float*)d_in[1];
    const float* Wp    = (const float*)d_in[2];
    const float* Wg    = (const float*)d_in[3];
    const float* Wo    = (const float*)d_in[4];
    const float* gamma = (const float*)d_in[5];
    float* out = (float*)d_out;
    unsigned short* ws = (unsigned short*)d_ws;

    k_proj<<<512, 256, 0, stream>>>(x, Wt, Wp, Wg, ws);
    k_attn<<<1024, 256, 0, stream>>>(x, Wo, gamma, ws, out);
}

// Round 5
// 132.031 us; speedup vs baseline: 1.2972x; 1.2972x over previous
//
#include <hip/hip_runtime.h>
#include <math.h>

// Problem constants
#define NB   16
#define NC   64
#define HWs  4096
#define NPS  1024
#define LOG2E 1.44269504088896341f

// ws layout in ushort (bf16 bit patterns)
static constexpr size_t PHI_OFF = (size_t)NB * HWs * 8;            // theta: [b][4096][8]
static constexpr size_t GT_OFF  = PHI_OFF + (size_t)NB * NPS * 8;  // phi:   [b][1024][8]
// gT: [b][32][1024]; total 1,179,648 ushorts = 2.25 MB

typedef short s16x8 __attribute__((ext_vector_type(8)));
typedef float f32x4 __attribute__((ext_vector_type(4)));

#define LD8G(p) (*(const s16x8*)(p))

__device__ inline unsigned short f2bf(float f) {
    unsigned int u = __float_as_uint(f);
    u += 0x7fffu + ((u >> 16) & 1u);          // RNE
    return (unsigned short)(u >> 16);
}
__device__ inline unsigned int pk2(float a, float b) {
    unsigned int ua = __float_as_uint(a); ua += 0x7fffu + ((ua >> 16) & 1u);
    unsigned int ub = __float_as_uint(b); ub += 0x7fffu + ((ub >> 16) & 1u);
    return (ua >> 16) | (ub & 0xffff0000u);
}

// ---------------------------------------------------------------------------
// Kernel 1 (v3): all projections in one pass, x staged through LDS.
// Same structure as v2, but `half` is forced into an SGPR via readfirstlane
// so ALL weight accesses compile to s_load (v2 accidentally generated 1536
// per-lane global_load_dword per thread -> ~70 us).
// ---------------------------------------------------------------------------
__global__ __launch_bounds__(256) void k_proj(
    const float* __restrict__ x, const float* __restrict__ Wt,
    const float* __restrict__ Wp, const float* __restrict__ Wg,
    unsigned short* __restrict__ ws)
{
    __shared__ float xs[64 * 128];            // 32 KB

    unsigned short* theta = ws;
    unsigned short* phi   = ws + PHI_OFF;
    unsigned short* gT    = ws + GT_OFF;

    const int tid = threadIdx.x;
    const int blk = blockIdx.x;
    const int b   = blk >> 5;
    const int rp  = blk & 31;                 // image rows {2rp, 2rp+1}

    // ---- stage x[b][ci][rp*128 .. +128) -> xs[ci][0..128) ----
    const float* xsrc = x + (size_t)b * NC * HWs + rp * 128;
#pragma unroll
    for (int i = 0; i < 8; ++i) {
        const int idx = i * 256 + tid;        // 0..2047 float4 slots
        const int ci  = idx >> 5;
        const int f4  = idx & 31;
        float4 v = *(const float4*)(xsrc + (size_t)ci * HWs + f4 * 4);
        *(float4*)(xs + ci * 128 + f4 * 4) = v;
    }
    __syncthreads();

    const int h    = tid & 127;
    // wave-uniform in fact (waves 0,1 -> 0; waves 2,3 -> 1); force to SGPR
    const int half = __builtin_amdgcn_readfirstlane(tid >> 7);
    const int row  = h & 1;
    const int col  = h >> 1;
    const int px   = row * 64 + col;

    float a8[8], ag[16];
#pragma unroll
    for (int j = 0; j < 8; ++j)  a8[j] = 0.f;
#pragma unroll
    for (int j = 0; j < 16; ++j) ag[j] = 0.f;

    const float* W8 = half ? Wp : Wt;         // scalar select (half is SGPR)
    const float* WG = Wg + half * 16 * NC;

#pragma unroll 4
    for (int ci = 0; ci < NC; ++ci) {
        const float xv = xs[ci * 128 + px];   // 2-way bank alias: free
#pragma unroll
        for (int j = 0; j < 8; ++j)  a8[j] += W8[j * NC + ci] * xv;   // s_load
#pragma unroll
        for (int j = 0; j < 16; ++j) ag[j] += WG[j * NC + ci] * xv;   // s_load
    }

    if (half == 0) {
        // theta: unpooled, scaled by log2e
        const int q = (2 * rp + row) * 64 + col;
        uint4 pkd;
        pkd.x = pk2(a8[0] * LOG2E, a8[1] * LOG2E);
        pkd.y = pk2(a8[2] * LOG2E, a8[3] * LOG2E);
        pkd.z = pk2(a8[4] * LOG2E, a8[5] * LOG2E);
        pkd.w = pk2(a8[6] * LOG2E, a8[7] * LOG2E);
        *(uint4*)(theta + ((size_t)b * HWs + q) * 8) = pkd;
    }

    // pooled max: row pair (h^1) then col pair (h^2) — both within-wave
#pragma unroll
    for (int j = 0; j < 8; ++j) {
        float v = a8[j];
        v = fmaxf(v, __shfl_xor(v, 1));
        v = fmaxf(v, __shfl_xor(v, 2));
        a8[j] = v;
    }
#pragma unroll
    for (int j = 0; j < 16; ++j) {
        float v = ag[j];
        v = fmaxf(v, __shfl_xor(v, 1));
        v = fmaxf(v, __shfl_xor(v, 2));
        ag[j] = v;
    }

    if ((h & 3) == 0) {
        const int ps = rp * 32 + (h >> 2);
        if (half == 1) {
            uint4 pkd;
            pkd.x = pk2(a8[0], a8[1]); pkd.y = pk2(a8[2], a8[3]);
            pkd.z = pk2(a8[4], a8[5]); pkd.w = pk2(a8[6], a8[7]);
            *(uint4*)(phi + ((size_t)b * NPS + ps) * 8) = pkd;
        }
#pragma unroll
        for (int j = 0; j < 16; ++j) {
            const int c = half * 16 + j;
            gT[((size_t)b * 32 + c) * NPS + ps] = f2bf(ag[j]);
        }
    }
}

// ---------------------------------------------------------------------------
// Kernel 2 (v3): MFMA attention, software-pipelined.
// Round-4 analysis: 74 us at MfmaUtil 4%, VALUBusy 32%, HBM 5% = per-tile
// serial chain (vmem waits + LDS write->read turnaround) was exposed.
// v3: prefetch phB(t+1) and Gf(t) into registers each iter; PV lags one
// tile using double-buffered P in LDS; Pf ds_read issued before exp/write.
// Math identical to round 4 (no online softmax; |S*log2e| < ~6 so plain
// exp2 is safe; l4 accumulates in the O register layout, no bridges).
// ---------------------------------------------------------------------------
__global__ __launch_bounds__(256) void k_attn(
    const float* __restrict__ x, const float* __restrict__ Wo,
    const float* __restrict__ gamma_p, const unsigned short* __restrict__ ws,
    float* __restrict__ out)
{
    __shared__ __align__(16) unsigned char smem[18432]; // P: 4 waves x 2 bufs x 16 x 72 x 2B; epilogue otile[32][68] f32

    const int tid  = threadIdx.x;
    const int wave = __builtin_amdgcn_readfirstlane(tid >> 6);
    const int lane = tid & 63;
    const int quad = lane >> 4, lr = lane & 15;
    const int blk  = blockIdx.x;
    const int b    = blk >> 6;
    const int q0   = (blk & 63) * 64;

    const unsigned short* th = ws + (size_t)b * HWs * 8;
    const unsigned short* ph = ws + PHI_OFF + (size_t)b * NPS * 8;
    const unsigned short* gp = ws + GT_OFF + (size_t)b * 32 * NPS;
    unsigned short* Pw = (unsigned short*)smem + wave * 2304;   // 2 bufs x [16 q][72 s]

    const s16x8 zf = {0, 0, 0, 0, 0, 0, 0, 0};

    // theta A-fragment: A[m=q=lr][k=quad*8+j], real k<8 in quad 0
    const s16x8 thA = (quad == 0) ? LD8G(th + (size_t)(q0 + wave * 16 + lr) * 8) : zf;

    f32x4 O[2];
    f32x4 l4;
#pragma unroll
    for (int r = 0; r < 4; ++r) { O[0][r] = 0.f; O[1][r] = 0.f; l4[r] = 0.f; }

    // pipeline registers
    s16x8 phB_c[4], phB_n[4];
    s16x8 Gf_c[2][2], Gf_n[2][2];
#pragma unroll
    for (int ss = 0; ss < 4; ++ss)
        phB_c[ss] = (quad == 0) ? LD8G(ph + (size_t)(ss * 16 + lr) * 8) : zf;

    for (int t = 0; t < 16; ++t) {
        const int s0 = t * 64;
        const int sn = (t < 15 ? t + 1 : 15) * 64;

        // ---- prefetch next phB and this tile's Gf (consumed next iter) ----
#pragma unroll
        for (int ss = 0; ss < 4; ++ss)
            phB_n[ss] = (quad == 0) ? LD8G(ph + (size_t)(sn + ss * 16 + lr) * 8) : zf;
#pragma unroll
        for (int kc = 0; kc < 2; ++kc)
#pragma unroll
            for (int cs = 0; cs < 2; ++cs)
                Gf_n[kc][cs] = LD8G(gp + (size_t)(cs * 16 + lr) * NPS + s0 + kc * 32 + quad * 8);

        // ---- scores for tile t (phB_c prefetched last iter) ----
        const f32x4 zc = {0.f, 0.f, 0.f, 0.f};
        f32x4 S[4];
#pragma unroll
        for (int ss = 0; ss < 4; ++ss)
            S[ss] = __builtin_amdgcn_mfma_f32_16x16x32_bf16(thA, phB_c[ss], zc, 0, 0, 0);

        // ---- lagged PV for tile t-1 (P read from buf (t-1)&1, Gf_c prefetched) ----
        if (t > 0) {
            const unsigned short* Pb = Pw + ((t - 1) & 1) * 1152;
#pragma unroll
            for (int kc = 0; kc < 2; ++kc) {
                const s16x8 Pf = *(const s16x8*)(Pb + lr * 72 + kc * 32 + quad * 8);
#pragma unroll
                for (int cs = 0; cs < 2; ++cs)
                    O[cs] = __builtin_amdgcn_mfma_f32_16x16x32_bf16(Pf, Gf_c[kc][cs], O[cs], 0, 0, 0);
            }
        }

        // ---- p = exp2(S), accumulate l, store bf16 P to buf t&1 ----
        unsigned short* Pbw = Pw + (t & 1) * 1152;
#pragma unroll
        for (int ss = 0; ss < 4; ++ss)
#pragma unroll
            for (int r = 0; r < 4; ++r) {
                const float p = exp2f(S[ss][r]);
                l4[r] += p;
                Pbw[(quad * 4 + r) * 72 + ss * 16 + lr] =
                    (unsigned short)(__float_as_uint(p) >> 16);   // truncate
            }

        // ---- rotate pipeline ----
#pragma unroll
        for (int ss = 0; ss < 4; ++ss) phB_c[ss] = phB_n[ss];
#pragma unroll
        for (int kc = 0; kc < 2; ++kc)
#pragma unroll
            for (int cs = 0; cs < 2; ++cs) Gf_c[kc][cs] = Gf_n[kc][cs];
    }

    // ---- drain: PV for tile 15 ----
    {
        const unsigned short* Pb = Pw + (15 & 1) * 1152;
#pragma unroll
        for (int kc = 0; kc < 2; ++kc) {
            const s16x8 Pf = *(const s16x8*)(Pb + lr * 72 + kc * 32 + quad * 8);
#pragma unroll
            for (int cs = 0; cs < 2; ++cs)
                O[cs] = __builtin_amdgcn_mfma_f32_16x16x32_bf16(Pf, Gf_c[kc][cs], O[cs], 0, 0, 0);
        }
    }

    // l: butterfly-sum over the 16-lane s-groups; O rows share the same q map
#pragma unroll
    for (int r = 0; r < 4; ++r) {
        float v = l4[r];
        v += __shfl_xor(v, 1);
        v += __shfl_xor(v, 2);
        v += __shfl_xor(v, 4);
        v += __shfl_xor(v, 8);
        l4[r] = 1.f / v;
    }

    __syncthreads();                          // all waves done with their Pw
    float* otile = (float*)smem;              // [32 c][68 q-stride]
#pragma unroll
    for (int cs = 0; cs < 2; ++cs) {
        f32x4 v;
#pragma unroll
        for (int r = 0; r < 4; ++r) v[r] = O[cs][r] * l4[r];
        *(f32x4*)(otile + (cs * 16 + lr) * 68 + wave * 16 + quad * 4) = v;
    }
    __syncthreads();

    // Wo epilogue + residual: thread = (q = tid&63, oc quarter = tid>>6)
    const int qq = tid & 63;
    const int quarter = __builtin_amdgcn_readfirstlane(tid >> 6); // SGPR -> s_load Wo
    float acc[16];
#pragma unroll
    for (int j = 0; j < 16; ++j) acc[j] = 0.f;
    for (int c = 0; c < 32; ++c) {
        const float ov = otile[c * 68 + qq];
#pragma unroll
        for (int j = 0; j < 16; ++j)
            acc[j] += Wo[(quarter * 16 + j) * 32 + c] * ov;   // s_load
    }
    const float gam = gamma_p[0];
#pragma unroll
    for (int j = 0; j < 16; ++j) {
        const size_t a = ((size_t)b * NC + quarter * 16 + j) * HWs + q0 + qq;
        out[a] = gam * acc[j] + x[a];
    }
}

extern "C" void kernel_launch(void* const* d_in, const int* in_sizes, int n_in,
                              void* d_out, int out_size, void* d_ws, size_t ws_size,
                              hipStream_t stream) {
    const float* x     = (const float*)d_in[0];
    const float* Wt    = (const float*)d_in[1];
    const float* Wp    = (const float*)d_in[2];
    const float* Wg    = (const float*)d_in[3];
    const float* Wo    = (const float*)d_in[4];
    const float* gamma = (const float*)d_in[5];
    float* out = (float*)d_out;
    unsigned short* ws = (unsigned short*)d_ws;

    k_proj<<<512, 256, 0, stream>>>(x, Wt, Wp, Wg, ws);
    k_attn<<<1024, 256, 0, stream>>>(x, Wo, gamma, ws, out);
}